// Round 1
// baseline (242.265 us; speedup 1.0000x reference)
//
#include <hip/hip_runtime.h>
#include <hip/hip_bf16.h>

// MyMSA: B=4 S=2048 D=1024 H=16 DH=64. fp32 in/out. bf16 MFMA, fp32 accum.
//
// R8 changes vs R6/R7 best (181.9 us):
//  * attn_kernel: LDS-free flash attention. qt=4 (64 q rows/wave), K and V
//    fragments read DIRECTLY from global (L2-resident: 512KB K/V per bh,
//    all 16 q-blocks of a bh pinned to one XCD by the bid&63 swizzle).
//    Removes 20 LDS instrs + 1 barrier per 64-key tile (LDS pipe was ~60%
//    busy, SQ_LDS_BANK_CONFLICT 8.4M). Register double-buffer: K/V frags
//    prefetched one 32-key phase (~250cy) ahead of use >= L2 latency.
//    2048 waves -> 2 waves/SIMD; unlike R7 (barrier-synced, starved),
//    waves here are barrier-free with prefetched operands.
//    L2 read = 16KB/wave/tile * 32 tiles * 2048 waves = 1.0GB (~19TB/s
//    at 50us, vs 34.5TB/s ceiling; qt=2 would be 2x = infeasible).
//  * qkv_kernel: grid 512->1024 (128-token chunks, 2 g-groups/wave) and
//    __launch_bounds__(256,3): 12 waves/CU (was 8 at 2 blocks/CU) to cover
//    the per-group x-load latency. Math/layouts unchanged.

typedef unsigned short u16;
typedef unsigned int   u32;
typedef float  f32x4  __attribute__((ext_vector_type(4)));
typedef __bf16 bf16x4 __attribute__((ext_vector_type(4)));
typedef __bf16 bf16x8 __attribute__((ext_vector_type(8)));

#define NB 4
#define SS 2048
#define DDIM 1024
#define NH 16
#define DH 64

static __device__ __forceinline__ float fexp2(float x) {
#if __has_builtin(__builtin_amdgcn_exp2f)
    return __builtin_amdgcn_exp2f(x);
#else
    return exp2f(x);
#endif
}
static __device__ __forceinline__ bf16x4 cvt4(f32x4 v) {
    return __builtin_convertvector(v, bf16x4);   // v_cvt_pk_bf16_f32 on gfx950
}
static __device__ __forceinline__ bf16x8 cvt8(f32x4 lo, f32x4 hi) {
    return __builtin_shufflevector(cvt4(lo), cvt4(hi), 0, 1, 2, 3, 4, 5, 6, 7);
}

// ---------------- Kernel 1: QKV projection ----------------
// grid: 64 * 16 = 1024 blocks (bh = bid&63 -> co-XCD with attn), 256 threads.
#define WST 72   // W_lds row stride (u16): 144B

__global__ __launch_bounds__(256, 3) void qkv_kernel(
        const float* __restrict__ x,
        const float* __restrict__ Wq, const float* __restrict__ bq,
        const float* __restrict__ Wk, const float* __restrict__ bk,
        const float* __restrict__ Wv, const float* __restrict__ bv,
        u16* __restrict__ Qw, u16* __restrict__ Kw, u16* __restrict__ Vt) {
    __shared__ __align__(16) u16 W_lds[3 * DH * WST];   // 27.6 KB

    const int tid  = threadIdx.x;
    const int w    = tid >> 6;
    const int lane = tid & 63;
    const int quad = lane >> 4;
    const int c    = lane & 15;
    const int bid  = blockIdx.x;
    const int bh   = bid & 63;
    const int s0   = (bid >> 6) * 128;
    const int b    = bh >> 4, h = bh & 15;

    // stage W fp32 -> bf16 into LDS
    {
        const float* Wsrc[3] = {Wq + h*DH*DH, Wk + h*DH*DH, Wv + h*DH*DH};
        #pragma unroll
        for (int j = 0; j < 6; ++j) {
            const int m = j >> 1;
            const int chunk = ((j & 1) << 8) + tid;      // 0..511 within mat
            const float* src = Wsrc[m] + chunk * 8;
            f32x4 lo = *(const f32x4*)src;
            f32x4 hi = *(const f32x4*)(src + 4);
            const int row = chunk >> 3, c8 = chunk & 7;
            *(bf16x8*)&W_lds[(m*DH + row) * WST + c8*8] = cvt8(lo, hi);
        }
    }
    __syncthreads();

    // per-wave W fragments, read from LDS ONCE, reused over 2 token groups
    bf16x8 wf[3][4][2];
    #pragma unroll
    for (int m = 0; m < 3; ++m)
        #pragma unroll
        for (int mt = 0; mt < 4; ++mt)
            #pragma unroll
            for (int kh = 0; kh < 2; ++kh)
                wf[m][mt][kh] = *(const bf16x8*)&W_lds[(m*DH + mt*16 + c) * WST + kh*32 + quad*8];

    f32x4 biasQK[2][4];
    float biasV[4];
    #pragma unroll
    for (int mt = 0; mt < 4; ++mt) {
        biasQK[0][mt] = *(const f32x4*)(bq + h*DH + mt*16 + quad*4);
        biasQK[1][mt] = *(const f32x4*)(bk + h*DH + mt*16 + quad*4);
        biasV[mt] = bv[h*DH + mt*16 + c];
    }

    const size_t qkbase = (size_t)bh * SS * DH;
    const size_t vtbase = (size_t)bh * DH * SS;

    #pragma unroll 1
    for (int g = 0; g < 2; ++g) {
        const int sb = s0 + w*32 + g*16;      // group tokens: sb + c
        const float* xr = x + ((size_t)(b * SS + sb + c)) * DDIM + h * DH;
        bf16x8 xb[2];
        #pragma unroll
        for (int kh = 0; kh < 2; ++kh) {
            f32x4 lo = *(const f32x4*)(xr + kh*32 + quad*8);
            f32x4 hi = *(const f32x4*)(xr + kh*32 + quad*8 + 4);
            xb[kh] = cvt8(lo, hi);
        }

        const int srow = sb + c;
        const int tq = srow & 31;
        const int sK = (srow & ~31) | ((tq & 4) << 2) | ((tq >> 3) << 2) | (tq & 3);

        // Q, K: swapped operands (A = W frag, B = X^T frag)
        #pragma unroll
        for (int m = 0; m < 2; ++m) {
            const float scale = (m == 0) ? 0.18033688f : 1.0f;  // 0.125*log2(e)
            u16* base = (m == 0 ? Qw : Kw) + qkbase + (size_t)(m == 0 ? srow : sK) * DH;
            #pragma unroll
            for (int mt = 0; mt < 4; ++mt) {
                f32x4 acc = {0.f, 0.f, 0.f, 0.f};
                acc = __builtin_amdgcn_mfma_f32_16x16x32_bf16(wf[m][mt][0], xb[0], acc, 0, 0, 0);
                acc = __builtin_amdgcn_mfma_f32_16x16x32_bf16(wf[m][mt][1], xb[1], acc, 0, 0, 0);
                f32x4 v = (acc + biasQK[m][mt]) * scale;
                *(bf16x4*)(base + mt*16 + quad*4) = cvt4(v);     // b64 store
            }
        }
        // V: non-swapped (A = X frag, B = W frag) -> C rows = tokens
        #pragma unroll
        for (int nt = 0; nt < 4; ++nt) {
            f32x4 acc = {0.f, 0.f, 0.f, 0.f};
            acc = __builtin_amdgcn_mfma_f32_16x16x32_bf16(xb[0], wf[2][nt][0], acc, 0, 0, 0);
            acc = __builtin_amdgcn_mfma_f32_16x16x32_bf16(xb[1], wf[2][nt][1], acc, 0, 0, 0);
            f32x4 v = acc + biasV[nt];
            u16* dst = Vt + vtbase + (size_t)(nt*16 + c) * SS + sb + quad*4;
            *(bf16x4*)dst = cvt4(v);                             // b64 along s
        }
    }
}

// ---------------- Kernel 2: flash attention, LDS-free ----------------
// grid: 64 * 16 = 1024 blocks, 128 threads (2 waves x 64 q rows, qt=4).
// K/V frags read straight from L2; register double-buffer one 32-key
// phase ahead. No __shared__, no barriers.

#define ATTN_LOAD(kf, vf, t) do {                                              \
        kf[0] = *(const bf16x8*)(Kc + (size_t)(t) * DH);                       \
        kf[1] = *(const bf16x8*)(Kc + (size_t)(t) * DH + 32);                  \
        kf[2] = *(const bf16x8*)(Kc + (size_t)((t) + 16) * DH);                \
        kf[3] = *(const bf16x8*)(Kc + (size_t)((t) + 16) * DH + 32);           \
        vf[0] = *(const bf16x8*)(Vc + (size_t)(t));                            \
        vf[1] = *(const bf16x8*)(Vc + (size_t)16 * SS + (t));                  \
        vf[2] = *(const bf16x8*)(Vc + (size_t)32 * SS + (t));                  \
        vf[3] = *(const bf16x8*)(Vc + (size_t)48 * SS + (t));                  \
    } while (0)

#define ATTN_PHASE(kf, vf)                                                     \
    _Pragma("unroll")                                                          \
    for (int qt = 0; qt < 4; ++qt) {                                           \
        f32x4 sA = {0.f,0.f,0.f,0.f}, sB = {0.f,0.f,0.f,0.f};                  \
        sA = __builtin_amdgcn_mfma_f32_16x16x32_bf16(kf[0], qf[qt][0], sA, 0,0,0); \
        sA = __builtin_amdgcn_mfma_f32_16x16x32_bf16(kf[1], qf[qt][1], sA, 0,0,0); \
        sB = __builtin_amdgcn_mfma_f32_16x16x32_bf16(kf[2], qf[qt][0], sB, 0,0,0); \
        sB = __builtin_amdgcn_mfma_f32_16x16x32_bf16(kf[3], qf[qt][1], sB, 0,0,0); \
        f32x4 eA, eB;                                                          \
        _Pragma("unroll")                                                      \
        for (int r = 0; r < 4; ++r) { eA[r] = fexp2(sA[r]); eB[r] = fexp2(sB[r]); } \
        bf16x8 pf = cvt8(eA, eB);                                              \
        _Pragma("unroll")                                                      \
        for (int dt = 0; dt < 4; ++dt)                                         \
            o[dt][qt] = __builtin_amdgcn_mfma_f32_16x16x32_bf16(vf[dt], pf, o[dt][qt], 0,0,0); \
        lacc[qt] = __builtin_amdgcn_mfma_f32_16x16x32_bf16(ones8, pf, lacc[qt], 0,0,0); \
    }

__global__ __launch_bounds__(128, 2) void attn_kernel(
        const u16* __restrict__ Qw, const u16* __restrict__ Kw,
        const u16* __restrict__ Vt, float* __restrict__ out) {
    const int tid  = threadIdx.x;
    const int w    = tid >> 6;
    const int lane = tid & 63;
    const int quad = lane >> 4;
    const int c    = lane & 15;
    const int bid  = blockIdx.x;
    const int bh   = bid & 63;           // XCD swizzle: same bh -> same XCD
    const int q0   = (bid >> 6) * 128;
    const int qw   = q0 + w * 64;        // wave's 64 q-rows (4 qt)

    const u16* Qb = Qw + (size_t)bh * SS * DH;
    // per-lane fragment base pointers (same data->register map as the old
    // staged path: staging was a linear row copy, so direct reads are
    // byte-identical, K row permutation included)
    const u16* Kc = Kw + (size_t)bh * SS * DH + (size_t)c * DH + quad * 8;
    const u16* Vc = Vt + (size_t)bh * DH * SS + (size_t)c * SS + quad * 8;

    // Q B-frags (n=q=c, k=d=quad*8+j)
    bf16x8 qf[4][2];
    #pragma unroll
    for (int qt = 0; qt < 4; ++qt) {
        const u16* qrow = Qb + (size_t)(qw + qt*16 + c) * DH;
        qf[qt][0] = *(const bf16x8*)(qrow + quad*8);
        qf[qt][1] = *(const bf16x8*)(qrow + 32 + quad*8);
    }

    f32x4 o[4][4];      // o[dt][qt]: O^T C-frags (col=q, row=d-local)
    f32x4 lacc[4];
    #pragma unroll
    for (int qt = 0; qt < 4; ++qt) {
        lacc[qt] = (f32x4){0.f, 0.f, 0.f, 0.f};
        #pragma unroll
        for (int dt = 0; dt < 4; ++dt) o[dt][qt] = (f32x4){0.f, 0.f, 0.f, 0.f};
    }

    bf16x8 ones8;
    { union { u16 u[8]; bf16x8 v; } one;
      #pragma unroll
      for (int i = 0; i < 8; ++i) one.u[i] = 0x3F80;
      ones8 = one.v; }

    // register double-buffer: phase = one 32-key group
    bf16x8 kf0[4], vf0[4], kf1[4], vf1[4];

    ATTN_LOAD(kf0, vf0, 0);
    #pragma unroll 1
    for (int t0 = 0; t0 < SS; t0 += 64) {
        ATTN_LOAD(kf1, vf1, t0 + 32);          // prefetch next phase
        ATTN_PHASE(kf0, vf0);
        const int tn = (t0 + 64 < SS) ? (t0 + 64) : 0;   // wrap: dead load
        ATTN_LOAD(kf0, vf0, tn);
        ATTN_PHASE(kf1, vf1);
    }

    // epilogue: lane holds token = qw + qt*16 + c, d = dt*16 + quad*4 + r
    const int b = bh >> 4, h = bh & 15;
    #pragma unroll
    for (int qt = 0; qt < 4; ++qt) {
        const float inv = 1.0f / lacc[qt][0];
        const int token = qw + qt*16 + c;
        float* orow = out + ((size_t)b * SS + token) * DDIM + h * DH;
        #pragma unroll
        for (int dt = 0; dt < 4; ++dt) {
            f32x4 vv = o[dt][qt] * inv;
            *(f32x4*)(orow + dt*16 + quad*4) = vv;
        }
    }
}

extern "C" void kernel_launch(void* const* d_in, const int* in_sizes, int n_in,
                              void* d_out, int out_size, void* d_ws, size_t ws_size,
                              hipStream_t stream) {
    const float* x  = (const float*)d_in[0];
    const float* Wq = (const float*)d_in[1];
    const float* bq = (const float*)d_in[2];
    const float* Wk = (const float*)d_in[3];
    const float* bk = (const float*)d_in[4];
    const float* Wv = (const float*)d_in[5];
    const float* bv = (const float*)d_in[6];

    // ws: Qw[bh][s][d], Kw[bh][s'][d] (s permuted per 32), Vt[bh][d][s]
    u16* Qw = (u16*)d_ws;
    u16* Kw = Qw + (size_t)NB * NH * SS * DH;
    u16* Vt = Kw + (size_t)NB * NH * SS * DH;

    qkv_kernel<<<64 * (SS / 128), 256, 0, stream>>>(
        x, Wq, bq, Wk, bk, Wv, bv, Qw, Kw, Vt);
    attn_kernel<<<64 * (SS / 128), 128, 0, stream>>>(Qw, Kw, Vt, (float*)d_out);
}